// Round 1
// baseline (248.190 us; speedup 1.0000x reference)
//
#include <hip/hip_runtime.h>
#include <hip/hip_bf16.h>

// Problem: B=32, H=512, W=512, C=4 float32.
//   m00 = max(0.001, sum(mk)); m10 = sum((x-256)*mk); m01 = sum((y-256)*mk)
//   d = round_half_even(m10/m00, m01/m00)  per batch (int)
//   out[b,i,j,c] = x[b, i+dy, j+dx, c] if in range else 0   (zero pad, NOT clamp)

#define RB 32          // reduction blocks per batch
#define NB 32          // batches
#define HPIX 512
#define WPIX 512
#define PIX_PER_BATCH (HPIX * WPIX)       // 262144

// ---------------- kernel 1: per-batch partial moments ----------------
// grid = NB*RB blocks x 256 threads. Each block reduces 2048 float4 (8192 mk
// values = 16 rows) deterministically; writes 3 partial floats.
__global__ __launch_bounds__(256) void moments_kernel(const float* __restrict__ mk,
                                                      float* __restrict__ partials) {
    const int b   = blockIdx.x / RB;
    const int blk = blockIdx.x % RB;
    const int tid = threadIdx.x;

    const float4* mk4 = (const float4*)(mk + (size_t)b * PIX_PER_BATCH);
    float a0 = 0.f, ax = 0.f, ay = 0.f;
    const int base = blk * 2048 + tid;   // float4 index within batch
#pragma unroll
    for (int it = 0; it < 8; ++it) {
        const int q = base + it * 256;       // float4 index
        const float4 v = mk4[q];
        const int p  = q << 2;               // float index within batch
        const int y  = p >> 9;               // row
        const int x0 = p & 511;              // col of v.x
        const float wy = (float)(y - 256);
        const float s  = v.x + v.y + v.z + v.w;
        a0 += s;
        ay += wy * s;
        ax += (float)(x0 - 256) * v.x + (float)(x0 - 255) * v.y +
              (float)(x0 - 254) * v.z + (float)(x0 - 253) * v.w;
    }
    __shared__ float r0[256], rx[256], ry[256];
    r0[tid] = a0; rx[tid] = ax; ry[tid] = ay;
    __syncthreads();
    for (int s = 128; s > 0; s >>= 1) {
        if (tid < s) {
            r0[tid] += r0[tid + s];
            rx[tid] += rx[tid + s];
            ry[tid] += ry[tid + s];
        }
        __syncthreads();
    }
    if (tid == 0) {
        float* pb = partials + (size_t)(b * RB + blk) * 3;
        pb[0] = r0[0]; pb[1] = rx[0]; pb[2] = ry[0];
    }
}

// ---------------- kernel 2: finalize per-batch integer shift ----------------
__global__ void finalize_kernel(const float* __restrict__ partials,
                                int2* __restrict__ d) {
    const int b = threadIdx.x;
    if (b < NB) {
        float s0 = 0.f, sx = 0.f, sy = 0.f;
        for (int i = 0; i < RB; ++i) {
            const float* p = partials + (size_t)(b * RB + i) * 3;
            s0 += p[0]; sx += p[1]; sy += p[2];
        }
        const float m00 = fmaxf(0.001f, s0);
        // jnp.round = round half to even = rintf under default rounding mode
        d[b] = make_int2((int)rintf(sx / m00), (int)rintf(sy / m00));
    }
}

// ---------------- kernel 3: shifted copy (zero outside) ----------------
// one thread per pixel (float4 = 4 channels), fully coalesced.
__global__ __launch_bounds__(256) void shift_kernel(const float4* __restrict__ x,
                                                    const int2* __restrict__ d,
                                                    float4* __restrict__ out) {
    const int gid = blockIdx.x * 256 + threadIdx.x;   // pixel index
    const int b  = gid >> 18;                          // / 262144
    const int ij = gid & (PIX_PER_BATCH - 1);
    const int i  = ij >> 9;                            // row
    const int j  = ij & 511;                           // col
    const int2 db = d[b];
    const int sx = j + db.x;
    const int sy = i + db.y;
    float4 v = make_float4(0.f, 0.f, 0.f, 0.f);
    if ((unsigned)sx < (unsigned)WPIX && (unsigned)sy < (unsigned)HPIX) {
        v = x[((size_t)b << 18) + (sy << 9) + sx];
    }
    out[gid] = v;
}

extern "C" void kernel_launch(void* const* d_in, const int* in_sizes, int n_in,
                              void* d_out, int out_size, void* d_ws, size_t ws_size,
                              hipStream_t stream) {
    const float* x  = (const float*)d_in[0];   // [32,512,512,4]
    const float* mk = (const float*)d_in[1];   // [32,512,512,1]
    float* out = (float*)d_out;                // [32,512,512,4]

    float* partials = (float*)d_ws;                                  // 3*NB*RB floats
    int2*  d        = (int2*)((char*)d_ws + (size_t)3 * NB * RB * sizeof(float)); // 8B aligned (12288)

    moments_kernel<<<NB * RB, 256, 0, stream>>>(mk, partials);
    finalize_kernel<<<1, 64, 0, stream>>>(partials, d);
    shift_kernel<<<(NB * PIX_PER_BATCH) / 256, 256, 0, stream>>>(
        (const float4*)x, d, (float4*)out);
}